// Round 1
// baseline (654.834 us; speedup 1.0000x reference)
//
#include <hip/hip_runtime.h>

// Problem constants (fixed by reference)
constexpr int B_ROWS = 65536;
constexpr int IN_F   = 1024;
constexpr int OUT_F  = 1024;

constexpr int BDIM = 256;          // 4 waves
constexpr int BM = 128, BN = 128, BK = 32;

typedef __bf16 bf16x8 __attribute__((ext_vector_type(8)));
typedef float  f32x4  __attribute__((ext_vector_type(4)));

__device__ __forceinline__ bf16x8 cvt8(f32x4 u0, f32x4 u1) {
    bf16x8 v;
    v[0] = (__bf16)u0[0]; v[1] = (__bf16)u0[1]; v[2] = (__bf16)u0[2]; v[3] = (__bf16)u0[3];
    v[4] = (__bf16)u1[0]; v[5] = (__bf16)u1[1]; v[6] = (__bf16)u1[2]; v[7] = (__bf16)u1[3];
    return v;
}

// async global->LDS, 16B per lane (wave stages 1KB contiguous at uniform lds base)
__device__ __forceinline__ void glds16(const __bf16* g, unsigned char* l) {
    __builtin_amdgcn_global_load_lds(
        (const __attribute__((address_space(1))) unsigned int*)(const void*)g,
        (__attribute__((address_space(3))) unsigned int*)(void*)l,
        16, 0, 0);
}

// Counted barrier: retires the 2 B-DMAs for the tile we're about to compute,
// leaves the 4 A-prefetch register loads in flight (never vmcnt(0) in-loop).
#define BAR_CNT() asm volatile("s_waitcnt vmcnt(4) lgkmcnt(0)\n\ts_barrier" ::: "memory")
// Last K-step: its A-prefetch loads are dead (DCE'd) -> count 4 would be wrong.
#define BAR_ALL() asm volatile("s_waitcnt vmcnt(0) lgkmcnt(0)\n\ts_barrier" ::: "memory")

// ---------------- W f32 -> bf16 pre-convert (2 MB, runs once per launch) -------------
__global__ __launch_bounds__(256)
void w_to_bf16(const float* __restrict__ W, __bf16* __restrict__ Wb) {
    const int i = (blockIdx.x * 256 + threadIdx.x) * 8;
    f32x4 a = *(const f32x4*)(W + i);
    f32x4 b = *(const f32x4*)(W + i + 4);
    *(bf16x8*)(Wb + i) = cvt8(a, b);
}

// ---------------- fused GEMM + bias + cyclic activation ------------------------------
__global__ __launch_bounds__(BDIM, 4)
void fused_linear_act(const float* __restrict__ X,    // [B_ROWS][IN_F] f32
                      const __bf16* __restrict__ Wb,  // [OUT_F][IN_F] bf16 (pre-converted)
                      const float* __restrict__ bias, // [OUT_F]
                      float* __restrict__ O)          // [B_ROWS][OUT_F]
{
    // LDS: 2 buffers x (A 8KB | B 8KB), MFMA-order layout:
    // 16B unit(row,kq) = (row>>4)*64 + kq*16 + (row&15). Every wave-level
    // ds_read_b128/ds_write_b128/global_load_lds is a contiguous 1KB block.
    __shared__ __attribute__((aligned(16))) unsigned char lds[2 * 16384];

    const int bx  = blockIdx.x;
    // XCD-aware: 8 consecutive blocks per XCD share one A panel (L2 reuse).
    const int xcd = bx & 7;
    const int idx = bx >> 3;
    const int nt  = idx & 7;
    const int mt  = xcd + 8 * (idx >> 3);
    const int m0 = mt * BM;
    const int n0 = nt * BN;

    const int tid  = threadIdx.x;
    const int lane = tid & 63;
    const int wave = tid >> 6;
    const int wm = (wave >> 1) * 64;
    const int wn = (wave & 1) * 64;
    const int lrow = lane & 15;
    const int quad = lane >> 4;

    // A staging: thread -> (row srow, 8-float k-segment sseg)
    const int srow = tid >> 2;        // 0..63 (+64 for second half)
    const int sseg = tid & 3;

    f32x4 acc[4][4];
    #pragma unroll
    for (int i = 0; i < 4; ++i)
        #pragma unroll
        for (int j = 0; j < 4; ++j)
            acc[i][j] = (f32x4){0.f, 0.f, 0.f, 0.f};

    const float* xa = X + (size_t)(m0 + srow) * IN_F + sseg * 8;
    const float* xb = xa + (size_t)64 * IN_F;

    // B source (per-lane, pre-swizzled to MFMA-order): wave w stages LDS blocks
    // {w, w+4}; within a block: row = 16*blk + (lane&15), kseg = (lane>>4)*8.
    const __bf16* wsrc0 = Wb + (size_t)(n0 + 16 * wave + lrow) * IN_F + quad * 8;
    const __bf16* wsrc1 = wsrc0 + (size_t)64 * IN_F;
    unsigned char* ldsB0 = lds + 8192 + wave * 1024;   // uniform per wave
    unsigned char* ldsB1 = ldsB0 + 4096;

    // A write address; all destinations are immediate offsets
    unsigned char* wr = &lds[((srow >> 4) * 64 + sseg * 16 + (srow & 15)) * 16];
    const unsigned char* rdA = &lds[(wm >> 4) * 1024 + lane * 16];
    const unsigned char* rdB = &lds[8192 + (wn >> 4) * 1024 + lane * 16];

    // A prefetch registers (1 tile ahead) + B(0) DMA
    f32x4 A00 = *(const f32x4*)(xa);
    f32x4 A01 = *(const f32x4*)(xa + 4);
    f32x4 A10 = *(const f32x4*)(xb);
    f32x4 A11 = *(const f32x4*)(xb + 4);
    glds16(wsrc0, ldsB0);                    // B(0) -> buf0
    glds16(wsrc1, ldsB1);
    __builtin_amdgcn_sched_barrier(0);       // pin issue order (vmcnt arithmetic)

    int koffA = 0;
    int koffB = 0;

    auto stageA = [&](int buf) {
        unsigned char* w = wr + buf * 16384;
        *(bf16x8*)(w +    0) = cvt8(A00, A01);   // A rows 0..63
        *(bf16x8*)(w + 4096) = cvt8(A10, A11);   // A rows 64..127
        koffA = (koffA + BK) & (IN_F - 1);       // wrap on last iter (dead loads)
        A00 = *(const f32x4*)(xa + koffA); A01 = *(const f32x4*)(xa + koffA + 4);
        A10 = *(const f32x4*)(xb + koffA); A11 = *(const f32x4*)(xb + koffA + 4);
    };
    auto stageB = [&](int buf) {             // B for NEXT tile into buf (after barrier:
        koffB += BK;                         //  all waves done reading that buffer)
        glds16(wsrc0 + koffB, ldsB0 + buf * 16384);
        glds16(wsrc1 + koffB, ldsB1 + buf * 16384);
        __builtin_amdgcn_sched_barrier(0);   // keep later A-loads after these DMAs
    };
    auto compute = [&](int buf) {
        const unsigned char* ra = rdA + buf * 16384;
        const unsigned char* rb = rdB + buf * 16384;
        bf16x8 af[4], bfr[4];
        #pragma unroll
        for (int t = 0; t < 4; ++t) af[t]  = *(const bf16x8*)(ra + t * 1024);
        #pragma unroll
        for (int t = 0; t < 4; ++t) bfr[t] = *(const bf16x8*)(rb + t * 1024);
        #pragma unroll
        for (int i = 0; i < 4; ++i)
            #pragma unroll
            for (int j = 0; j < 4; ++j)
                acc[i][j] = __builtin_amdgcn_mfma_f32_16x16x32_bf16(af[i], bfr[j], acc[i][j], 0, 0, 0);
    };

    // steady state at BAR_CNT: in-flight = [B(k) x2 (older), A(k+1) x4 (newer)]
    // -> vmcnt(4) retires exactly B(k); A prefetch stays in flight across barrier.
    #pragma unroll 1
    for (int it = 0; it < IN_F / BK - 2; it += 2) {
        stageA(0); BAR_CNT(); stageB(1); compute(0);
        stageA(1); BAR_CNT(); stageB(0); compute(1);
    }
    // peel last two K-steps (no stray B DMA; final A loads are dead -> vmcnt(0))
    stageA(0); BAR_CNT(); stageB(1); compute(0);
    stageA(1); BAR_ALL(); compute(1);

    // Epilogue: bias + cyclic activation; selector = col%4 = lane&3 (branchless)
    const int s = lane & 3;
    const float kmul = (s == 0) ? -2.f : -1.f;
    const float aa   = (s == 0) ?  2.f :  1.f;
    const float cc   = (s == 0) ? -1.f :  0.f;
    const bool  is_sin  = (s == 1);
    const bool  is_relu = (s == 2);

    #pragma unroll
    for (int j = 0; j < 4; ++j) {
        const int gc = n0 + wn + j * 16 + lrow;
        const float bv = bias[gc];
        #pragma unroll
        for (int i = 0; i < 4; ++i) {
            const int gr0 = m0 + wm + i * 16 + quad * 4;
            float* op = O + (size_t)gr0 * OUT_F + gc;
            #pragma unroll
            for (int r = 0; r < 4; ++r) {
                const float y = acc[i][j][r] + bv;
                const float e = __expf(kmul * y);
                const float g = fmaf(aa, __builtin_amdgcn_rcpf(1.f + e), cc);
                const float sv = __sinf(y);
                const float rv = fmaxf(y, 0.f);
                const float res = is_sin ? sv : (is_relu ? rv : g);
                op[(size_t)r * OUT_F] = res;
            }
        }
    }
}

extern "C" void kernel_launch(void* const* d_in, const int* in_sizes, int n_in,
                              void* d_out, int out_size, void* d_ws, size_t ws_size,
                              hipStream_t stream) {
    const float* X = (const float*)d_in[0];
    const float* W = (const float*)d_in[1];
    const float* b = (const float*)d_in[2];
    float* O = (float*)d_out;
    __bf16* Wb = (__bf16*)d_ws;   // 2 MB of workspace for bf16 W

    w_to_bf16<<<(OUT_F * IN_F) / (256 * 8), 256, 0, stream>>>(W, Wb);

    const int grid = (B_ROWS / BM) * (OUT_F / BN);  // 4096 blocks
    fused_linear_act<<<grid, BDIM, 0, stream>>>(X, Wb, b, O);
}